// Round 8
// baseline (232.199 us; speedup 1.0000x reference)
//
#include <hip/hip_runtime.h>
#include <hip/hip_bf16.h>

#define N_NODES 40000
#define N_EDGES 640000
#define DIM     128
#define NB      157    // node blocks (256 threads)
#define GEMMB   625    // gemm blocks (64 rows each)
#define HEB     1250   // hist/scatter blocks (2 edges/thread)

typedef __attribute__((ext_vector_type(8))) short short8;
typedef __attribute__((ext_vector_type(4))) float f32x4;

__device__ inline short f2bf(float f) {
    __hip_bfloat16 h = __float2bfloat16(f);
    return *reinterpret_cast<short*>(&h);
}
__device__ inline float bf2f(short u) {
    union { unsigned int i; float f; } x;
    x.i = ((unsigned int)(unsigned short)u) << 16;
    return x.f;
}

// fragment-order index for element (k,n) of a 128x128 W, matching the
// MFMA B-fragment read: lane l reads slot (kb*8+nt)*64 + l as short8.
__device__ inline int fragidx(int k, int n) {
    int kb = k >> 5, kq = (k >> 3) & 3, j = k & 7;
    int nt = n >> 4, nl = n & 15;
    return (((kb * 8 + nt) * 64 + kq * 16 + nl) * 8 + j);
}

// ---------------------------------------------------------------------------
// Dispatch 2: blocks [0,64) = weight prep; [64, 64+HEB) = edge histogram.
// ---------------------------------------------------------------------------
__global__ __launch_bounds__(256) void hist_prep(const int* __restrict__ rows,
                                                 int* __restrict__ counts,
                                                 const float* __restrict__ Wt,
                                                 const float* __restrict__ W0,
                                                 const float* __restrict__ W1,
                                                 const float* __restrict__ bt,
                                                 short* __restrict__ WtF,
                                                 short* __restrict__ WfF,
                                                 short* __restrict__ W1F,
                                                 float* __restrict__ btf) {
    int b = blockIdx.x;
    if (b < 64) {
        int gid = b * 256 + threadIdx.x;            // 0..16383
        int k = gid >> 7, n = gid & 127;
        float wf = 0.f;
        for (int kk = 0; kk < 128; ++kk)
            wf += Wt[k * 128 + kk] * W0[kk * 128 + n];
        int fi = fragidx(k, n);
        WtF[fi] = f2bf(Wt[k * 128 + n]);
        W1F[fi] = f2bf(W1[k * 128 + n]);
        WfF[fi] = f2bf(wf);
        if (gid < 128) {
            float s = 0.f;
            for (int kk = 0; kk < 128; ++kk) s += bt[kk] * W0[kk * 128 + n];
            btf[n] = s;
        }
    } else {
        int gid = (b - 64) * 256 + threadIdx.x;     // 0..319999
        atomicAdd(&counts[rows[gid]], 1);
        atomicAdd(&counts[rows[gid + HEB * 256]], 1);
    }
}

// ---------------------------------------------------------------------------
// Dispatch 3: single-pass scan. 157 blocks (guaranteed co-resident).
// Each block: local inclusive scan of its 256 counts; publish block total
// (device-scope atomic + fence + flag, published BEFORE any wait -> no
// deadlock); spin for all flags; scan totals in LDS; emit cursor/row_ptr.
// ---------------------------------------------------------------------------
__global__ __launch_bounds__(256) void scan_onepass(const int* __restrict__ counts,
                                                    int* __restrict__ totals,
                                                    int* __restrict__ flags,
                                                    int* __restrict__ cursor,
                                                    int* __restrict__ row_ptr) {
    __shared__ int sh[256];
    const int b = blockIdx.x;
    const int t = threadIdx.x;
    const int i = b * 256 + t;

    int c = (i < N_NODES) ? counts[i] : 0;
    int val = c;
    sh[t] = val;
    __syncthreads();
    for (int off = 1; off < 256; off <<= 1) {
        int a = (t >= off) ? sh[t - off] : 0;
        __syncthreads();
        val += a;
        sh[t] = val;
        __syncthreads();
    }
    const int excl  = val - c;       // exclusive prefix within block
    const int total = sh[255];

    if (t == 0) {
        atomicExch(&totals[b], total);
        __threadfence();
        atomicExch(&flags[b], 1);
    }

    int v = 0;
    if (t < NB) {
        while (atomicAdd(&flags[t], 0) == 0) { }
        v = atomicAdd(&totals[t], 0);
    }
    __syncthreads();
    int val2 = v;
    sh[t] = val2;
    __syncthreads();
    for (int off = 1; off < 256; off <<= 1) {
        int a = (t >= off) ? sh[t - off] : 0;
        __syncthreads();
        val2 += a;
        sh[t] = val2;
        __syncthreads();
    }
    int blkOff = (b == 0) ? 0 : sh[b - 1];

    if (i < N_NODES) {
        int u = excl + blkOff;
        cursor[i]  = u;
        row_ptr[i] = u;
    }
    if (i == 0) row_ptr[N_NODES] = N_EDGES;
}

// ---------------------------------------------------------------------------
// Dispatch 4: blocks [0,HEB) = scatter (FIRST: tiny latency-bound blocks
// grab slots early; 5000 scatter waves + 2500 gemm waves <= 8192 device
// slots so both stay resident and the GEMM hides the atomic latency);
// blocks [HEB, HEB+GEMMB) = dual GEMM over x:
//   H = x@Wt + bt (fp32, d_out), Z0 = bf16(x@(Wt@W0) + bt@W0)
// ---------------------------------------------------------------------------
__global__ __launch_bounds__(256) void dualgemm_scatter(const float* __restrict__ A,
                                                        const short* __restrict__ WtF,
                                                        const short* __restrict__ WfF,
                                                        const float* __restrict__ bt,
                                                        const float* __restrict__ btf,
                                                        float* __restrict__ H,
                                                        __hip_bfloat16* __restrict__ Z,
                                                        const int* __restrict__ rows,
                                                        const int* __restrict__ cols,
                                                        int* __restrict__ cursor,
                                                        unsigned short* __restrict__ adj) {
    if (blockIdx.x < HEB) {
        int gid = blockIdx.x * 256 + threadIdx.x;   // 0..319999
#pragma unroll
        for (int h = 0; h < 2; ++h) {
            int e   = gid + h * HEB * 256;
            int r   = rows[e];
            int pos = atomicAdd(&cursor[r], 1);
            adj[pos] = (unsigned short)cols[e];
        }
        return;
    }

    const int t    = threadIdx.x;
    const int wave = t >> 6;
    const int l    = t & 63;
    const int nl   = l & 15;
    const int quad = l >> 4;
    const int wRow = (blockIdx.x - HEB) * 64 + wave * 16;

    f32x4 accH[8], accZ[8];
#pragma unroll
    for (int nt = 0; nt < 8; ++nt) {
        accH[nt] = (f32x4){0.f, 0.f, 0.f, 0.f};
        accZ[nt] = (f32x4){0.f, 0.f, 0.f, 0.f};
    }

#pragma unroll
    for (int kb = 0; kb < 4; ++kb) {
        const float* ap = A + (size_t)(wRow + nl) * 128 + kb * 32 + quad * 8;
        float4 f0 = *(const float4*)ap;
        float4 f1 = *(const float4*)(ap + 4);
        short8 afrag;
        afrag[0] = f2bf(f0.x); afrag[1] = f2bf(f0.y);
        afrag[2] = f2bf(f0.z); afrag[3] = f2bf(f0.w);
        afrag[4] = f2bf(f1.x); afrag[5] = f2bf(f1.y);
        afrag[6] = f2bf(f1.z); afrag[7] = f2bf(f1.w);
#pragma unroll
        for (int nt = 0; nt < 8; ++nt) {
            int off = ((kb * 8 + nt) * 64 + l) * 8;
            short8 bt_frag = *(const short8*)&WtF[off];
            short8 bf_frag = *(const short8*)&WfF[off];
            accH[nt] = __builtin_amdgcn_mfma_f32_16x16x32_bf16(afrag, bt_frag, accH[nt], 0, 0, 0);
            accZ[nt] = __builtin_amdgcn_mfma_f32_16x16x32_bf16(afrag, bf_frag, accZ[nt], 0, 0, 0);
        }
    }

#pragma unroll
    for (int nt = 0; nt < 8; ++nt) {
        int col = nt * 16 + nl;
        float bH = bt[col];
        float bZ = btf[col];
#pragma unroll
        for (int r = 0; r < 4; ++r) {
            int row = wRow + quad * 4 + r;
            H[(size_t)row * 128 + col] = accH[nt][r] + bH;
            *(short*)&Z[(size_t)row * 128 + col] = f2bf(accZ[nt][r] + bZ);
        }
    }
}

// ---------------------------------------------------------------------------
// Dispatch 5: fused layer-0 agg + layer-1 GEMM.
// 16 nodes/block. Phase 1: wave w gathers nodes w*4+u from Z0, computes
// hnew = H[node] + relu(agg+b0) (fp32), writes H in place (own rows only),
// stages bf16(hnew) in padded LDS. Phase 2: Z1[16x128] = hs @ W1 -> Z1
// buffer (DISTINCT from Z0 — no aliasing with concurrent gatherers).
// ---------------------------------------------------------------------------
__global__ __launch_bounds__(256) void agg0_gemm(const __hip_bfloat16* __restrict__ z0,
                                                 const int* __restrict__ row_ptr,
                                                 const unsigned short* __restrict__ adj,
                                                 const float* __restrict__ bias,
                                                 const short* __restrict__ W1F,
                                                 float* __restrict__ H,
                                                 __hip_bfloat16* __restrict__ Z1) {
    __shared__ short hs[16][136];   // +8 shorts pad

    const int t    = threadIdx.x;
    const int wave = t >> 6;
    const int l    = t & 63;
    const int quad = l >> 4;
    const int sl   = l & 15;
    const int nodeBase = blockIdx.x * 16;

#pragma unroll
    for (int u = 0; u < 4; ++u) {
        const int m    = wave * 4 + u;
        const int node = nodeBase + m;
        const int s = row_ptr[node];
        const int e = row_ptr[node + 1];

        float acc[8];
#pragma unroll
        for (int j = 0; j < 8; ++j) acc[j] = 0.f;

        int it = s + quad;
        for (; it + 12 < e; it += 16) {
            int c0 = adj[it];
            int c1 = adj[it + 4];
            int c2 = adj[it + 8];
            int c3 = adj[it + 12];
            short8 v0 = *(const short8*)&z0[(size_t)c0 * DIM + sl * 8];
            short8 v1 = *(const short8*)&z0[(size_t)c1 * DIM + sl * 8];
            short8 v2 = *(const short8*)&z0[(size_t)c2 * DIM + sl * 8];
            short8 v3 = *(const short8*)&z0[(size_t)c3 * DIM + sl * 8];
#pragma unroll
            for (int j = 0; j < 8; ++j)
                acc[j] += (bf2f(v0[j]) + bf2f(v1[j])) + (bf2f(v2[j]) + bf2f(v3[j]));
        }
        for (; it + 4 < e; it += 8) {
            int c0 = adj[it];
            int c1 = adj[it + 4];
            short8 v0 = *(const short8*)&z0[(size_t)c0 * DIM + sl * 8];
            short8 v1 = *(const short8*)&z0[(size_t)c1 * DIM + sl * 8];
#pragma unroll
            for (int j = 0; j < 8; ++j) acc[j] += bf2f(v0[j]) + bf2f(v1[j]);
        }
        if (it < e) {
            int c = adj[it];
            short8 v = *(const short8*)&z0[(size_t)c * DIM + sl * 8];
#pragma unroll
            for (int j = 0; j < 8; ++j) acc[j] += bf2f(v[j]);
        }

#pragma unroll
        for (int j = 0; j < 8; ++j) acc[j] += __shfl_xor(acc[j], 16, 64);
#pragma unroll
        for (int j = 0; j < 8; ++j) acc[j] += __shfl_xor(acc[j], 32, 64);

        if (quad == 0) {
            float* hp = H + (size_t)node * DIM + sl * 8;
            float4 h0 = *(float4*)hp;
            float4 h1 = *(float4*)(hp + 4);
            float4 b0v = *(const float4*)&bias[sl * 8];
            float4 b1v = *(const float4*)&bias[sl * 8 + 4];
            float r[8];
            r[0] = acc[0] + b0v.x; r[1] = acc[1] + b0v.y; r[2] = acc[2] + b0v.z; r[3] = acc[3] + b0v.w;
            r[4] = acc[4] + b1v.x; r[5] = acc[5] + b1v.y; r[6] = acc[6] + b1v.z; r[7] = acc[7] + b1v.w;
            float hn[8];
            hn[0] = h0.x; hn[1] = h0.y; hn[2] = h0.z; hn[3] = h0.w;
            hn[4] = h1.x; hn[5] = h1.y; hn[6] = h1.z; hn[7] = h1.w;
            short8 o;
#pragma unroll
            for (int j = 0; j < 8; ++j) {
                float rr = r[j] > 0.f ? r[j] : 0.f;
                hn[j] += rr;
                o[j] = f2bf(hn[j]);
            }
            *(float4*)hp       = make_float4(hn[0], hn[1], hn[2], hn[3]);
            *(float4*)(hp + 4) = make_float4(hn[4], hn[5], hn[6], hn[7]);
            *(short8*)&hs[m][sl * 8] = o;
        }
    }
    __syncthreads();

    // phase 2: Z1[16x128] = hs @ W1 ; wave handles cols [wave*32, wave*32+32)
    f32x4 acc2[2];
    acc2[0] = (f32x4){0.f, 0.f, 0.f, 0.f};
    acc2[1] = (f32x4){0.f, 0.f, 0.f, 0.f};
#pragma unroll
    for (int kb = 0; kb < 4; ++kb) {
        short8 afrag = *(const short8*)&hs[sl][kb * 32 + quad * 8];
#pragma unroll
        for (int nt2 = 0; nt2 < 2; ++nt2) {
            int nt = wave * 2 + nt2;
            short8 bfrag = *(const short8*)&W1F[((kb * 8 + nt) * 64 + l) * 8];
            acc2[nt2] = __builtin_amdgcn_mfma_f32_16x16x32_bf16(afrag, bfrag, acc2[nt2], 0, 0, 0);
        }
    }
#pragma unroll
    for (int nt2 = 0; nt2 < 2; ++nt2) {
        int col = (wave * 2 + nt2) * 16 + sl;
#pragma unroll
        for (int r = 0; r < 4; ++r) {
            int row = nodeBase + quad * 4 + r;
            *(short*)&Z1[(size_t)row * 128 + col] = f2bf(acc2[nt2][r]);
        }
    }
}

// ---------------------------------------------------------------------------
// Dispatch 6: final aggregation. H[node] += relu(agg(Z1)+b1), own row only.
// ---------------------------------------------------------------------------
__global__ __launch_bounds__(256) void agg_final(const __hip_bfloat16* __restrict__ z,
                                                 const int* __restrict__ row_ptr,
                                                 const unsigned short* __restrict__ adj,
                                                 const float* __restrict__ bias,
                                                 float* __restrict__ H) {
    const int wave = threadIdx.x >> 6;
    const int l    = threadIdx.x & 63;
    const int quad = l >> 4;
    const int sl   = l & 15;
    const int node = blockIdx.x * 4 + wave;
    if (node >= N_NODES) return;

    const int s = row_ptr[node];
    const int e = row_ptr[node + 1];

    float acc[8];
#pragma unroll
    for (int j = 0; j < 8; ++j) acc[j] = 0.f;

    int it = s + quad;
    for (; it + 12 < e; it += 16) {
        int c0 = adj[it];
        int c1 = adj[it + 4];
        int c2 = adj[it + 8];
        int c3 = adj[it + 12];
        short8 v0 = *(const short8*)&z[(size_t)c0 * DIM + sl * 8];
        short8 v1 = *(const short8*)&z[(size_t)c1 * DIM + sl * 8];
        short8 v2 = *(const short8*)&z[(size_t)c2 * DIM + sl * 8];
        short8 v3 = *(const short8*)&z[(size_t)c3 * DIM + sl * 8];
#pragma unroll
        for (int j = 0; j < 8; ++j)
            acc[j] += (bf2f(v0[j]) + bf2f(v1[j])) + (bf2f(v2[j]) + bf2f(v3[j]));
    }
    for (; it + 4 < e; it += 8) {
        int c0 = adj[it];
        int c1 = adj[it + 4];
        short8 v0 = *(const short8*)&z[(size_t)c0 * DIM + sl * 8];
        short8 v1 = *(const short8*)&z[(size_t)c1 * DIM + sl * 8];
#pragma unroll
        for (int j = 0; j < 8; ++j) acc[j] += bf2f(v0[j]) + bf2f(v1[j]);
    }
    if (it < e) {
        int c = adj[it];
        short8 v = *(const short8*)&z[(size_t)c * DIM + sl * 8];
#pragma unroll
        for (int j = 0; j < 8; ++j) acc[j] += bf2f(v[j]);
    }

#pragma unroll
    for (int j = 0; j < 8; ++j) acc[j] += __shfl_xor(acc[j], 16, 64);
#pragma unroll
    for (int j = 0; j < 8; ++j) acc[j] += __shfl_xor(acc[j], 32, 64);

    if (quad == 0) {
        float* hp = H + (size_t)node * DIM + sl * 8;
        float4 h0 = *(float4*)hp;
        float4 h1 = *(float4*)(hp + 4);
        float4 b0 = *(const float4*)&bias[sl * 8];
        float4 b1 = *(const float4*)&bias[sl * 8 + 4];
        float r0 = acc[0] + b0.x, r1 = acc[1] + b0.y, r2 = acc[2] + b0.z, r3 = acc[3] + b0.w;
        float r4 = acc[4] + b1.x, r5 = acc[5] + b1.y, r6 = acc[6] + b1.z, r7 = acc[7] + b1.w;
        h0.x += r0 > 0.f ? r0 : 0.f;  h0.y += r1 > 0.f ? r1 : 0.f;
        h0.z += r2 > 0.f ? r2 : 0.f;  h0.w += r3 > 0.f ? r3 : 0.f;
        h1.x += r4 > 0.f ? r4 : 0.f;  h1.y += r5 > 0.f ? r5 : 0.f;
        h1.z += r6 > 0.f ? r6 : 0.f;  h1.w += r7 > 0.f ? r7 : 0.f;
        *(float4*)hp       = h0;
        *(float4*)(hp + 4) = h1;
    }
}

// ---------------------------------------------------------------------------
extern "C" void kernel_launch(void* const* d_in, const int* in_sizes, int n_in,
                              void* d_out, int out_size, void* d_ws, size_t ws_size,
                              hipStream_t stream) {
    const float* x   = (const float*)d_in[0];
    const int*   ei  = (const int*)d_in[1];
    const float* W_t = (const float*)d_in[2];
    const float* b_t = (const float*)d_in[3];
    const float* W0  = (const float*)d_in[4];
    const float* b0  = (const float*)d_in[5];
    const float* W1  = (const float*)d_in[6];
    const float* b1  = (const float*)d_in[7];

    const int* rows = ei;
    const int* cols = ei + N_EDGES;

    float* H = (float*)d_out;   // fp32 h lives here the whole time

    // workspace layout (~22.3 MB)
    char* w = (char*)d_ws;
    __hip_bfloat16* Z0 = (__hip_bfloat16*)w;  w += (size_t)N_NODES * DIM * 2;
    __hip_bfloat16* Z1 = (__hip_bfloat16*)w;  w += (size_t)N_NODES * DIM * 2;
    short* WtF = (short*)w;  w += 128 * 128 * 2;
    short* WfF = (short*)w;  w += 128 * 128 * 2;
    short* W1F = (short*)w;  w += 128 * 128 * 2;
    float* btf = (float*)w;  w += 128 * 4;
    int* row_ptr = (int*)w;  w += (N_NODES + 1) * 4;
    int* cursor  = (int*)w;  w += N_NODES * 4;
    int* counts  = (int*)w;  w += N_NODES * 4;     // zeroed by memset (with flags)
    int* flags   = (int*)w;  w += 256 * 4;         // zeroed by memset
    int* totals  = (int*)w;  w += 256 * 4;         // guarded by flags
    unsigned short* adj = (unsigned short*)w;      // E u16

    const int aggBlocks = (N_NODES + 3) / 4;

    // 1: zero counts + flags (contiguous)
    hipMemsetAsync(counts, 0, (N_NODES + 256) * sizeof(int), stream);

    // 2: weight prep | edge histogram
    hist_prep<<<64 + HEB, 256, 0, stream>>>(rows, counts, W_t, W0, W1, b_t,
                                            WtF, WfF, W1F, btf);

    // 3: single-pass scan -> row_ptr / cursor
    scan_onepass<<<NB, 256, 0, stream>>>(counts, totals, flags, cursor, row_ptr);

    // 4: scatter (first) | dual GEMM over x (hides scatter's atomic latency)
    dualgemm_scatter<<<HEB + GEMMB, 256, 0, stream>>>(x, WtF, WfF, b_t, btf, H, Z0,
                                                      rows, cols, cursor, adj);

    // 5: layer-0 agg + layer-1 GEMM fused: H += relu(agg(Z0)+b0); Z1 = bf16(H)@W1
    agg0_gemm<<<N_NODES / 16, 256, 0, stream>>>(Z0, row_ptr, adj, b0, W1F, H, Z1);

    // 6: final agg: H += relu(agg(Z1) + b1)
    agg_final<<<aggBlocks, 256, 0, stream>>>(Z1, row_ptr, adj, b1, H);
}

// Round 9
// 204.536 us; speedup vs baseline: 1.1352x; 1.1352x over previous
//
#include <hip/hip_runtime.h>
#include <hip/hip_bf16.h>

#define N_NODES 40000
#define N_EDGES 640000
#define DIM     128
#define NB      157    // node blocks (256 threads)
#define GEMMB   625    // gemm blocks (64 rows each)
#define HEB     1250   // hist/scatter blocks (2 edges/thread)

typedef __attribute__((ext_vector_type(8))) short short8;
typedef __attribute__((ext_vector_type(4))) float f32x4;

__device__ inline short f2bf(float f) {
    __hip_bfloat16 h = __float2bfloat16(f);
    return *reinterpret_cast<short*>(&h);
}
__device__ inline float bf2f(short u) {
    union { unsigned int i; float f; } x;
    x.i = ((unsigned int)(unsigned short)u) << 16;
    return x.f;
}

// fragment-order index for element (k,n) of a 128x128 W, matching the
// MFMA B-fragment read: lane l reads slot (kb*8+nt)*64 + l as short8.
__device__ inline int fragidx(int k, int n) {
    int kb = k >> 5, kq = (k >> 3) & 3, j = k & 7;
    int nt = n >> 4, nl = n & 15;
    return (((kb * 8 + nt) * 64 + kq * 16 + nl) * 8 + j);
}

// ---------------------------------------------------------------------------
// Dispatch 1: [0,64) weight prep; [64,64+NB) zero counts; last block zeros
// flags+totals. Replaces the hipMemsetAsync dispatch.
// ---------------------------------------------------------------------------
__global__ __launch_bounds__(256) void prep_zero(const float* __restrict__ Wt,
                                                 const float* __restrict__ W0,
                                                 const float* __restrict__ W1,
                                                 const float* __restrict__ bt,
                                                 short* __restrict__ WtF,
                                                 short* __restrict__ WfF,
                                                 short* __restrict__ W1F,
                                                 float* __restrict__ btf,
                                                 int* __restrict__ counts,
                                                 int* __restrict__ flagtot) {
    int b = blockIdx.x;
    if (b < 64) {
        int gid = b * 256 + threadIdx.x;            // 0..16383
        int k = gid >> 7, n = gid & 127;
        float wf = 0.f;
        for (int kk = 0; kk < 128; ++kk)
            wf += Wt[k * 128 + kk] * W0[kk * 128 + n];
        int fi = fragidx(k, n);
        WtF[fi] = f2bf(Wt[k * 128 + n]);
        W1F[fi] = f2bf(W1[k * 128 + n]);
        WfF[fi] = f2bf(wf);
        if (gid < 128) {
            float s = 0.f;
            for (int kk = 0; kk < 128; ++kk) s += bt[kk] * W0[kk * 128 + n];
            btf[n] = s;
        }
    } else if (b < 64 + NB) {
        int i = (b - 64) * 256 + threadIdx.x;
        if (i < N_NODES) counts[i] = 0;
    } else {
        flagtot[threadIdx.x]       = 0;   // flags
        flagtot[threadIdx.x + 256] = 0;   // totals
    }
}

// ---------------------------------------------------------------------------
// Dispatch 2: blocks [0,HEB) = histogram + rank (the atomicAdd return value
// IS the edge's slot within its destination bucket — saves the second
// atomic pass); blocks [HEB,HEB+GEMMB) = dual GEMM over x:
//   H = x@Wt + bt (fp32, d_out), Z0 = bf16(x@(Wt@W0) + bt@W0)
// ---------------------------------------------------------------------------
__global__ __launch_bounds__(256) void histrank_gemm(const int* __restrict__ rows,
                                                     int* __restrict__ counts,
                                                     unsigned short* __restrict__ rank,
                                                     const float* __restrict__ A,
                                                     const short* __restrict__ WtF,
                                                     const short* __restrict__ WfF,
                                                     const float* __restrict__ bt,
                                                     const float* __restrict__ btf,
                                                     float* __restrict__ H,
                                                     __hip_bfloat16* __restrict__ Z) {
    if (blockIdx.x < HEB) {
        int gid = blockIdx.x * 256 + threadIdx.x;   // 0..319999
#pragma unroll
        for (int h = 0; h < 2; ++h) {
            int e = gid + h * HEB * 256;
            int r = rows[e];
            rank[e] = (unsigned short)atomicAdd(&counts[r], 1);
        }
        return;
    }

    const int t    = threadIdx.x;
    const int wave = t >> 6;
    const int l    = t & 63;
    const int nl   = l & 15;
    const int quad = l >> 4;
    const int wRow = (blockIdx.x - HEB) * 64 + wave * 16;

    f32x4 accH[8], accZ[8];
#pragma unroll
    for (int nt = 0; nt < 8; ++nt) {
        accH[nt] = (f32x4){0.f, 0.f, 0.f, 0.f};
        accZ[nt] = (f32x4){0.f, 0.f, 0.f, 0.f};
    }

#pragma unroll
    for (int kb = 0; kb < 4; ++kb) {
        const float* ap = A + (size_t)(wRow + nl) * 128 + kb * 32 + quad * 8;
        float4 f0 = *(const float4*)ap;
        float4 f1 = *(const float4*)(ap + 4);
        short8 afrag;
        afrag[0] = f2bf(f0.x); afrag[1] = f2bf(f0.y);
        afrag[2] = f2bf(f0.z); afrag[3] = f2bf(f0.w);
        afrag[4] = f2bf(f1.x); afrag[5] = f2bf(f1.y);
        afrag[6] = f2bf(f1.z); afrag[7] = f2bf(f1.w);
#pragma unroll
        for (int nt = 0; nt < 8; ++nt) {
            int off = ((kb * 8 + nt) * 64 + l) * 8;
            short8 bt_frag = *(const short8*)&WtF[off];
            short8 bf_frag = *(const short8*)&WfF[off];
            accH[nt] = __builtin_amdgcn_mfma_f32_16x16x32_bf16(afrag, bt_frag, accH[nt], 0, 0, 0);
            accZ[nt] = __builtin_amdgcn_mfma_f32_16x16x32_bf16(afrag, bf_frag, accZ[nt], 0, 0, 0);
        }
    }

#pragma unroll
    for (int nt = 0; nt < 8; ++nt) {
        int col = nt * 16 + nl;
        float bH = bt[col];
        float bZ = btf[col];
#pragma unroll
        for (int r = 0; r < 4; ++r) {
            int row = wRow + quad * 4 + r;
            H[(size_t)row * 128 + col] = accH[nt][r] + bH;
            *(short*)&Z[(size_t)row * 128 + col] = f2bf(accZ[nt][r] + bZ);
        }
    }
}

// ---------------------------------------------------------------------------
// Dispatch 3: single-pass scan. 157 blocks (co-resident).
// Publish block total (atomic+fence+flag BEFORE waiting -> no deadlock),
// spin for all flags, scan totals in LDS, emit row_ptr.
// ---------------------------------------------------------------------------
__global__ __launch_bounds__(256) void scan_onepass(const int* __restrict__ counts,
                                                    int* __restrict__ flags,
                                                    int* __restrict__ totals,
                                                    int* __restrict__ row_ptr) {
    __shared__ int sh[256];
    const int b = blockIdx.x;
    const int t = threadIdx.x;
    const int i = b * 256 + t;

    int c = (i < N_NODES) ? counts[i] : 0;
    int val = c;
    sh[t] = val;
    __syncthreads();
    for (int off = 1; off < 256; off <<= 1) {
        int a = (t >= off) ? sh[t - off] : 0;
        __syncthreads();
        val += a;
        sh[t] = val;
        __syncthreads();
    }
    const int excl  = val - c;       // exclusive prefix within block
    const int total = sh[255];

    if (t == 0) {
        atomicExch(&totals[b], total);
        __threadfence();
        atomicExch(&flags[b], 1);
    }

    int v = 0;
    if (t < NB) {
        while (atomicAdd(&flags[t], 0) == 0) { }
        v = atomicAdd(&totals[t], 0);
    }
    __syncthreads();
    int val2 = v;
    sh[t] = val2;
    __syncthreads();
    for (int off = 1; off < 256; off <<= 1) {
        int a = (t >= off) ? sh[t - off] : 0;
        __syncthreads();
        val2 += a;
        sh[t] = val2;
        __syncthreads();
    }
    int blkOff = (b == 0) ? 0 : sh[b - 1];

    if (i < N_NODES) row_ptr[i] = excl + blkOff;
    if (i == 0) row_ptr[N_NODES] = N_EDGES;
}

// ---------------------------------------------------------------------------
// Dispatch 4: atomic-free scatter. pos = row_ptr[r] + rank[e].
// row_ptr is 160 KB -> L2-resident random reads; only the random u16
// write remains (line-amplified but cheap).
// ---------------------------------------------------------------------------
__global__ __launch_bounds__(256) void scatter_plain(const int* __restrict__ rows,
                                                     const int* __restrict__ cols,
                                                     const unsigned short* __restrict__ rank,
                                                     const int* __restrict__ row_ptr,
                                                     unsigned short* __restrict__ adj) {
    int gid = blockIdx.x * 256 + threadIdx.x;     // 0..319999
#pragma unroll
    for (int h = 0; h < 2; ++h) {
        int e = gid + h * HEB * 256;
        int r = rows[e];
        adj[row_ptr[r] + (int)rank[e]] = (unsigned short)cols[e];
    }
}

// ---------------------------------------------------------------------------
// Dispatch 5: fused layer-0 agg + layer-1 GEMM.
// 16 nodes/block. Phase 1: wave w gathers nodes w*4+u from Z0, computes
// hnew = H[node] + relu(agg+b0) (fp32), writes H in place (own rows only),
// stages bf16(hnew) in padded LDS. Phase 2: Z1[16x128] = hs @ W1 -> Z1
// buffer (distinct from Z0 — no aliasing with concurrent gatherers).
// ---------------------------------------------------------------------------
__global__ __launch_bounds__(256) void agg0_gemm(const __hip_bfloat16* __restrict__ z0,
                                                 const int* __restrict__ row_ptr,
                                                 const unsigned short* __restrict__ adj,
                                                 const float* __restrict__ bias,
                                                 const short* __restrict__ W1F,
                                                 float* __restrict__ H,
                                                 __hip_bfloat16* __restrict__ Z1) {
    __shared__ short hs[16][136];   // +8 shorts pad

    const int t    = threadIdx.x;
    const int wave = t >> 6;
    const int l    = t & 63;
    const int quad = l >> 4;
    const int sl   = l & 15;
    const int nodeBase = blockIdx.x * 16;

#pragma unroll
    for (int u = 0; u < 4; ++u) {
        const int m    = wave * 4 + u;
        const int node = nodeBase + m;
        const int s = row_ptr[node];
        const int e = row_ptr[node + 1];

        float acc[8];
#pragma unroll
        for (int j = 0; j < 8; ++j) acc[j] = 0.f;

        int it = s + quad;
        for (; it + 12 < e; it += 16) {
            int c0 = adj[it];
            int c1 = adj[it + 4];
            int c2 = adj[it + 8];
            int c3 = adj[it + 12];
            short8 v0 = *(const short8*)&z0[(size_t)c0 * DIM + sl * 8];
            short8 v1 = *(const short8*)&z0[(size_t)c1 * DIM + sl * 8];
            short8 v2 = *(const short8*)&z0[(size_t)c2 * DIM + sl * 8];
            short8 v3 = *(const short8*)&z0[(size_t)c3 * DIM + sl * 8];
#pragma unroll
            for (int j = 0; j < 8; ++j)
                acc[j] += (bf2f(v0[j]) + bf2f(v1[j])) + (bf2f(v2[j]) + bf2f(v3[j]));
        }
        for (; it + 4 < e; it += 8) {
            int c0 = adj[it];
            int c1 = adj[it + 4];
            short8 v0 = *(const short8*)&z0[(size_t)c0 * DIM + sl * 8];
            short8 v1 = *(const short8*)&z0[(size_t)c1 * DIM + sl * 8];
#pragma unroll
            for (int j = 0; j < 8; ++j) acc[j] += bf2f(v0[j]) + bf2f(v1[j]);
        }
        if (it < e) {
            int c = adj[it];
            short8 v = *(const short8*)&z0[(size_t)c * DIM + sl * 8];
#pragma unroll
            for (int j = 0; j < 8; ++j) acc[j] += bf2f(v[j]);
        }

#pragma unroll
        for (int j = 0; j < 8; ++j) acc[j] += __shfl_xor(acc[j], 16, 64);
#pragma unroll
        for (int j = 0; j < 8; ++j) acc[j] += __shfl_xor(acc[j], 32, 64);

        if (quad == 0) {
            float* hp = H + (size_t)node * DIM + sl * 8;
            float4 h0 = *(float4*)hp;
            float4 h1 = *(float4*)(hp + 4);
            float4 b0v = *(const float4*)&bias[sl * 8];
            float4 b1v = *(const float4*)&bias[sl * 8 + 4];
            float r[8];
            r[0] = acc[0] + b0v.x; r[1] = acc[1] + b0v.y; r[2] = acc[2] + b0v.z; r[3] = acc[3] + b0v.w;
            r[4] = acc[4] + b1v.x; r[5] = acc[5] + b1v.y; r[6] = acc[6] + b1v.z; r[7] = acc[7] + b1v.w;
            float hn[8];
            hn[0] = h0.x; hn[1] = h0.y; hn[2] = h0.z; hn[3] = h0.w;
            hn[4] = h1.x; hn[5] = h1.y; hn[6] = h1.z; hn[7] = h1.w;
            short8 o;
#pragma unroll
            for (int j = 0; j < 8; ++j) {
                float rr = r[j] > 0.f ? r[j] : 0.f;
                hn[j] += rr;
                o[j] = f2bf(hn[j]);
            }
            *(float4*)hp       = make_float4(hn[0], hn[1], hn[2], hn[3]);
            *(float4*)(hp + 4) = make_float4(hn[4], hn[5], hn[6], hn[7]);
            *(short8*)&hs[m][sl * 8] = o;
        }
    }
    __syncthreads();

    // phase 2: Z1[16x128] = hs @ W1 ; wave handles cols [wave*32, wave*32+32)
    f32x4 acc2[2];
    acc2[0] = (f32x4){0.f, 0.f, 0.f, 0.f};
    acc2[1] = (f32x4){0.f, 0.f, 0.f, 0.f};
#pragma unroll
    for (int kb = 0; kb < 4; ++kb) {
        short8 afrag = *(const short8*)&hs[sl][kb * 32 + quad * 8];
#pragma unroll
        for (int nt2 = 0; nt2 < 2; ++nt2) {
            int nt = wave * 2 + nt2;
            short8 bfrag = *(const short8*)&W1F[((kb * 8 + nt) * 64 + l) * 8];
            acc2[nt2] = __builtin_amdgcn_mfma_f32_16x16x32_bf16(afrag, bfrag, acc2[nt2], 0, 0, 0);
        }
    }
#pragma unroll
    for (int nt2 = 0; nt2 < 2; ++nt2) {
        int col = (wave * 2 + nt2) * 16 + sl;
#pragma unroll
        for (int r = 0; r < 4; ++r) {
            int row = nodeBase + quad * 4 + r;
            *(short*)&Z1[(size_t)row * 128 + col] = f2bf(acc2[nt2][r]);
        }
    }
}

// ---------------------------------------------------------------------------
// Dispatch 6: final aggregation. H[node] += relu(agg(Z1)+b1), own row only.
// ---------------------------------------------------------------------------
__global__ __launch_bounds__(256) void agg_final(const __hip_bfloat16* __restrict__ z,
                                                 const int* __restrict__ row_ptr,
                                                 const unsigned short* __restrict__ adj,
                                                 const float* __restrict__ bias,
                                                 float* __restrict__ H) {
    const int wave = threadIdx.x >> 6;
    const int l    = threadIdx.x & 63;
    const int quad = l >> 4;
    const int sl   = l & 15;
    const int node = blockIdx.x * 4 + wave;
    if (node >= N_NODES) return;

    const int s = row_ptr[node];
    const int e = row_ptr[node + 1];

    float acc[8];
#pragma unroll
    for (int j = 0; j < 8; ++j) acc[j] = 0.f;

    int it = s + quad;
    for (; it + 12 < e; it += 16) {
        int c0 = adj[it];
        int c1 = adj[it + 4];
        int c2 = adj[it + 8];
        int c3 = adj[it + 12];
        short8 v0 = *(const short8*)&z[(size_t)c0 * DIM + sl * 8];
        short8 v1 = *(const short8*)&z[(size_t)c1 * DIM + sl * 8];
        short8 v2 = *(const short8*)&z[(size_t)c2 * DIM + sl * 8];
        short8 v3 = *(const short8*)&z[(size_t)c3 * DIM + sl * 8];
#pragma unroll
        for (int j = 0; j < 8; ++j)
            acc[j] += (bf2f(v0[j]) + bf2f(v1[j])) + (bf2f(v2[j]) + bf2f(v3[j]));
    }
    for (; it + 4 < e; it += 8) {
        int c0 = adj[it];
        int c1 = adj[it + 4];
        short8 v0 = *(const short8*)&z[(size_t)c0 * DIM + sl * 8];
        short8 v1 = *(const short8*)&z[(size_t)c1 * DIM + sl * 8];
#pragma unroll
        for (int j = 0; j < 8; ++j) acc[j] += bf2f(v0[j]) + bf2f(v1[j]);
    }
    if (it < e) {
        int c = adj[it];
        short8 v = *(const short8*)&z[(size_t)c * DIM + sl * 8];
#pragma unroll
        for (int j = 0; j < 8; ++j) acc[j] += bf2f(v[j]);
    }

#pragma unroll
    for (int j = 0; j < 8; ++j) acc[j] += __shfl_xor(acc[j], 16, 64);
#pragma unroll
    for (int j = 0; j < 8; ++j) acc[j] += __shfl_xor(acc[j], 32, 64);

    if (quad == 0) {
        float* hp = H + (size_t)node * DIM + sl * 8;
        float4 h0 = *(float4*)hp;
        float4 h1 = *(float4*)(hp + 4);
        float4 b0 = *(const float4*)&bias[sl * 8];
        float4 b1 = *(const float4*)&bias[sl * 8 + 4];
        float r0 = acc[0] + b0.x, r1 = acc[1] + b0.y, r2 = acc[2] + b0.z, r3 = acc[3] + b0.w;
        float r4 = acc[4] + b1.x, r5 = acc[5] + b1.y, r6 = acc[6] + b1.z, r7 = acc[7] + b1.w;
        h0.x += r0 > 0.f ? r0 : 0.f;  h0.y += r1 > 0.f ? r1 : 0.f;
        h0.z += r2 > 0.f ? r2 : 0.f;  h0.w += r3 > 0.f ? r3 : 0.f;
        h1.x += r4 > 0.f ? r4 : 0.f;  h1.y += r5 > 0.f ? r5 : 0.f;
        h1.z += r6 > 0.f ? r6 : 0.f;  h1.w += r7 > 0.f ? r7 : 0.f;
        *(float4*)hp       = h0;
        *(float4*)(hp + 4) = h1;
    }
}

// ---------------------------------------------------------------------------
extern "C" void kernel_launch(void* const* d_in, const int* in_sizes, int n_in,
                              void* d_out, int out_size, void* d_ws, size_t ws_size,
                              hipStream_t stream) {
    const float* x   = (const float*)d_in[0];
    const int*   ei  = (const int*)d_in[1];
    const float* W_t = (const float*)d_in[2];
    const float* b_t = (const float*)d_in[3];
    const float* W0  = (const float*)d_in[4];
    const float* b0  = (const float*)d_in[5];
    const float* W1  = (const float*)d_in[6];
    const float* b1  = (const float*)d_in[7];

    const int* rows = ei;
    const int* cols = ei + N_EDGES;

    float* H = (float*)d_out;   // fp32 h lives here the whole time

    // workspace layout (~23 MB)
    char* w = (char*)d_ws;
    __hip_bfloat16* Z0 = (__hip_bfloat16*)w;  w += (size_t)N_NODES * DIM * 2;
    __hip_bfloat16* Z1 = (__hip_bfloat16*)w;  w += (size_t)N_NODES * DIM * 2;
    short* WtF = (short*)w;  w += 128 * 128 * 2;
    short* WfF = (short*)w;  w += 128 * 128 * 2;
    short* W1F = (short*)w;  w += 128 * 128 * 2;
    float* btf = (float*)w;  w += 128 * 4;
    int* row_ptr = (int*)w;  w += (N_NODES + 1) * 4;
    int* counts  = (int*)w;  w += N_NODES * 4;
    int* flags   = (int*)w;  w += 256 * 4;
    int* totals  = (int*)w;  w += 256 * 4;
    unsigned short* rank = (unsigned short*)w;  w += (size_t)N_EDGES * 2;
    unsigned short* adj  = (unsigned short*)w;  // E u16

    const int aggBlocks = (N_NODES + 3) / 4;

    // 1: weight prep | zero counts | zero flags+totals
    prep_zero<<<64 + NB + 1, 256, 0, stream>>>(W_t, W0, W1, b_t, WtF, WfF, W1F,
                                               btf, counts, flags);

    // 2: histogram+rank (one atomic pass total) | dual GEMM over x
    histrank_gemm<<<HEB + GEMMB, 256, 0, stream>>>(rows, counts, rank,
                                                   x, WtF, WfF, b_t, btf, H, Z0);

    // 3: single-pass scan -> row_ptr
    scan_onepass<<<NB, 256, 0, stream>>>(counts, flags, totals, row_ptr);

    // 4: atomic-free scatter
    scatter_plain<<<HEB, 256, 0, stream>>>(rows, cols, rank, row_ptr, adj);

    // 5: layer-0 agg + layer-1 GEMM fused: H += relu(agg(Z0)+b0); Z1 = bf16(H)@W1
    agg0_gemm<<<N_NODES / 16, 256, 0, stream>>>(Z0, row_ptr, adj, b0, W1F, H, Z1);

    // 6: final agg: H += relu(agg(Z1) + b1)
    agg_final<<<aggBlocks, 256, 0, stream>>>(Z1, row_ptr, adj, b1, H);
}

// Round 10
// 199.411 us; speedup vs baseline: 1.1644x; 1.0257x over previous
//
#include <hip/hip_runtime.h>
#include <hip/hip_bf16.h>

#define N_NODES 40000
#define N_EDGES 640000
#define DIM     128
#define NB      157    // node blocks (256 threads)
#define GEMMB   625    // gemm blocks (64 rows each)
#define HEB     1250   // hist/scatter blocks (2 edges/thread)
#define NREP    4      // histogram counter replicas (contention /4)

typedef __attribute__((ext_vector_type(8))) short short8;
typedef __attribute__((ext_vector_type(4))) float f32x4;
typedef __attribute__((ext_vector_type(2))) float f32x2;

__device__ inline short f2bf(float f) {
    __hip_bfloat16 h = __float2bfloat16(f);
    return *reinterpret_cast<short*>(&h);
}
__device__ inline float bf2f(short u) {
    union { unsigned int i; float f; } x;
    x.i = ((unsigned int)(unsigned short)u) << 16;
    return x.f;
}

// fragment-order index for element (k,n) of a 128x128 W, matching the
// MFMA B-fragment read: lane l reads slot (kb*8+nt)*64 + l as short8.
__device__ inline int fragidx(int k, int n) {
    int kb = k >> 5, kq = (k >> 3) & 3, j = k & 7;
    int nt = n >> 4, nl = n & 15;
    return (((kb * 8 + nt) * 64 + kq * 16 + nl) * 8 + j);
}

// ---------------------------------------------------------------------------
// Dispatch 1: [0,64) weight prep; [64,64+4*NB) zero counts4; last block
// zeros flags+totals.
// ---------------------------------------------------------------------------
__global__ __launch_bounds__(256) void prep_zero(const float* __restrict__ Wt,
                                                 const float* __restrict__ W0,
                                                 const float* __restrict__ W1,
                                                 const float* __restrict__ bt,
                                                 short* __restrict__ WtF,
                                                 short* __restrict__ WfF,
                                                 short* __restrict__ W1F,
                                                 float* __restrict__ btf,
                                                 int* __restrict__ counts4,
                                                 int* __restrict__ flagtot) {
    int b = blockIdx.x;
    if (b < 64) {
        int gid = b * 256 + threadIdx.x;            // 0..16383
        int k = gid >> 7, n = gid & 127;
        float wf = 0.f;
        for (int kk = 0; kk < 128; ++kk)
            wf += Wt[k * 128 + kk] * W0[kk * 128 + n];
        int fi = fragidx(k, n);
        WtF[fi] = f2bf(Wt[k * 128 + n]);
        W1F[fi] = f2bf(W1[k * 128 + n]);
        WfF[fi] = f2bf(wf);
        if (gid < 128) {
            float s = 0.f;
            for (int kk = 0; kk < 128; ++kk) s += bt[kk] * W0[kk * 128 + n];
            btf[n] = s;
        }
    } else if (b < 64 + NREP * NB) {
        int i = (b - 64) * 256 + threadIdx.x;
        if (i < NREP * N_NODES) counts4[i] = 0;
    } else {
        flagtot[threadIdx.x]       = 0;   // flags
        flagtot[threadIdx.x + 256] = 0;   // totals
    }
}

// ---------------------------------------------------------------------------
// Dispatch 2: blocks [0,HEB) = histogram+rank into replica (blockIdx&3)
// (atomicAdd return value = rank within replica bucket);
// blocks [HEB,HEB+GEMMB) = dual GEMM over x:
//   H = x@Wt + bt (fp32, d_out), Z0 = bf16(x@(Wt@W0) + bt@W0)
// ---------------------------------------------------------------------------
__global__ __launch_bounds__(256) void histrank_gemm(const int* __restrict__ rows,
                                                     int* __restrict__ counts4,
                                                     unsigned short* __restrict__ rank,
                                                     const float* __restrict__ A,
                                                     const short* __restrict__ WtF,
                                                     const short* __restrict__ WfF,
                                                     const float* __restrict__ bt,
                                                     const float* __restrict__ btf,
                                                     float* __restrict__ H,
                                                     __hip_bfloat16* __restrict__ Z) {
    if (blockIdx.x < HEB) {
        int gid = blockIdx.x * 256 + threadIdx.x;   // 0..319999
        int* cnt = counts4 + (blockIdx.x & (NREP - 1)) * N_NODES;
#pragma unroll
        for (int h = 0; h < 2; ++h) {
            int e = gid + h * HEB * 256;
            int r = rows[e];
            rank[e] = (unsigned short)atomicAdd(&cnt[r], 1);
        }
        return;
    }

    const int t    = threadIdx.x;
    const int wave = t >> 6;
    const int l    = t & 63;
    const int nl   = l & 15;
    const int quad = l >> 4;
    const int wRow = (blockIdx.x - HEB) * 64 + wave * 16;

    f32x4 accH[8], accZ[8];
#pragma unroll
    for (int nt = 0; nt < 8; ++nt) {
        accH[nt] = (f32x4){0.f, 0.f, 0.f, 0.f};
        accZ[nt] = (f32x4){0.f, 0.f, 0.f, 0.f};
    }

#pragma unroll
    for (int kb = 0; kb < 4; ++kb) {
        const float* ap = A + (size_t)(wRow + nl) * 128 + kb * 32 + quad * 8;
        float4 f0 = *(const float4*)ap;
        float4 f1 = *(const float4*)(ap + 4);
        short8 afrag;
        afrag[0] = f2bf(f0.x); afrag[1] = f2bf(f0.y);
        afrag[2] = f2bf(f0.z); afrag[3] = f2bf(f0.w);
        afrag[4] = f2bf(f1.x); afrag[5] = f2bf(f1.y);
        afrag[6] = f2bf(f1.z); afrag[7] = f2bf(f1.w);
#pragma unroll
        for (int nt = 0; nt < 8; ++nt) {
            int off = ((kb * 8 + nt) * 64 + l) * 8;
            short8 bt_frag = *(const short8*)&WtF[off];
            short8 bf_frag = *(const short8*)&WfF[off];
            accH[nt] = __builtin_amdgcn_mfma_f32_16x16x32_bf16(afrag, bt_frag, accH[nt], 0, 0, 0);
            accZ[nt] = __builtin_amdgcn_mfma_f32_16x16x32_bf16(afrag, bf_frag, accZ[nt], 0, 0, 0);
        }
    }

#pragma unroll
    for (int nt = 0; nt < 8; ++nt) {
        int col = nt * 16 + nl;
        float bH = bt[col];
        float bZ = btf[col];
#pragma unroll
        for (int r = 0; r < 4; ++r) {
            int row = wRow + quad * 4 + r;
            H[(size_t)row * 128 + col] = accH[nt][r] + bH;
            *(short*)&Z[(size_t)row * 128 + col] = f2bf(accZ[nt][r] + bZ);
        }
    }
}

// ---------------------------------------------------------------------------
// Dispatch 3: single-pass scan over per-node totals (sum of 4 replicas).
// Also emits absOff[r][node] = row_ptr[node] + (prefix of replicas < r),
// so the scatter needs exactly one random read per edge.
// Publish-then-spin flag pattern (publish BEFORE wait -> no deadlock).
// ---------------------------------------------------------------------------
__global__ __launch_bounds__(256) void scan_onepass(const int* __restrict__ counts4,
                                                    int* __restrict__ flags,
                                                    int* __restrict__ totals,
                                                    int* __restrict__ row_ptr,
                                                    int* __restrict__ absOff) {
    __shared__ int sh[256];
    const int b = blockIdx.x;
    const int t = threadIdx.x;
    const int i = b * 256 + t;

    int c0 = 0, c1 = 0, c2 = 0, c3 = 0;
    if (i < N_NODES) {
        c0 = counts4[0 * N_NODES + i];
        c1 = counts4[1 * N_NODES + i];
        c2 = counts4[2 * N_NODES + i];
        c3 = counts4[3 * N_NODES + i];
    }
    const int c = c0 + c1 + c2 + c3;

    int val = c;
    sh[t] = val;
    __syncthreads();
    for (int off = 1; off < 256; off <<= 1) {
        int a = (t >= off) ? sh[t - off] : 0;
        __syncthreads();
        val += a;
        sh[t] = val;
        __syncthreads();
    }
    const int excl  = val - c;       // exclusive prefix within block
    const int total = sh[255];

    if (t == 0) {
        atomicExch(&totals[b], total);
        __threadfence();
        atomicExch(&flags[b], 1);
    }

    int v = 0;
    if (t < NB) {
        while (atomicAdd(&flags[t], 0) == 0) { }
        v = atomicAdd(&totals[t], 0);
    }
    __syncthreads();
    int val2 = v;
    sh[t] = val2;
    __syncthreads();
    for (int off = 1; off < 256; off <<= 1) {
        int a = (t >= off) ? sh[t - off] : 0;
        __syncthreads();
        val2 += a;
        sh[t] = val2;
        __syncthreads();
    }
    int blkOff = (b == 0) ? 0 : sh[b - 1];

    if (i < N_NODES) {
        int base = excl + blkOff;
        row_ptr[i] = base;
        absOff[0 * N_NODES + i] = base;
        absOff[1 * N_NODES + i] = base + c0;
        absOff[2 * N_NODES + i] = base + c0 + c1;
        absOff[3 * N_NODES + i] = base + c0 + c1 + c2;
    }
    if (i == 0) row_ptr[N_NODES] = N_EDGES;
}

// ---------------------------------------------------------------------------
// Dispatch 4: atomic-free scatter. pos = absOff[replica][r] + rank[e].
// Same block->edge mapping as the hist, so replica = blockIdx & 3.
// ---------------------------------------------------------------------------
__global__ __launch_bounds__(256) void scatter_plain(const int* __restrict__ rows,
                                                     const int* __restrict__ cols,
                                                     const unsigned short* __restrict__ rank,
                                                     const int* __restrict__ absOff,
                                                     unsigned short* __restrict__ adj) {
    int gid = blockIdx.x * 256 + threadIdx.x;     // 0..319999
    const int* off = absOff + (blockIdx.x & (NREP - 1)) * N_NODES;
#pragma unroll
    for (int h = 0; h < 2; ++h) {
        int e = gid + h * HEB * 256;
        int r = rows[e];
        adj[off[r] + (int)rank[e]] = (unsigned short)cols[e];
    }
}

// ---------------------------------------------------------------------------
// Dispatch 5: fused layer-0 agg + layer-1 GEMM.
// Phase 1: gather Z0 (bf16), H += relu(agg+b0) in place, stage bf16(hnew)
// in padded LDS. Phase 2: Z1[16x128] = hs @ W1 -> fp8 e4m3 (HW cvt).
// ---------------------------------------------------------------------------
__global__ __launch_bounds__(256) void agg0_gemm(const __hip_bfloat16* __restrict__ z0,
                                                 const int* __restrict__ row_ptr,
                                                 const unsigned short* __restrict__ adj,
                                                 const float* __restrict__ bias,
                                                 const short* __restrict__ W1F,
                                                 float* __restrict__ H,
                                                 unsigned char* __restrict__ Z1) {
    __shared__ short hs[16][136];   // +8 shorts pad

    const int t    = threadIdx.x;
    const int wave = t >> 6;
    const int l    = t & 63;
    const int quad = l >> 4;
    const int sl   = l & 15;
    const int nodeBase = blockIdx.x * 16;

#pragma unroll
    for (int u = 0; u < 4; ++u) {
        const int m    = wave * 4 + u;
        const int node = nodeBase + m;
        const int s = row_ptr[node];
        const int e = row_ptr[node + 1];

        float acc[8];
#pragma unroll
        for (int j = 0; j < 8; ++j) acc[j] = 0.f;

        int it = s + quad;
        for (; it + 12 < e; it += 16) {
            int c0 = adj[it];
            int c1 = adj[it + 4];
            int c2 = adj[it + 8];
            int c3 = adj[it + 12];
            short8 v0 = *(const short8*)&z0[(size_t)c0 * DIM + sl * 8];
            short8 v1 = *(const short8*)&z0[(size_t)c1 * DIM + sl * 8];
            short8 v2 = *(const short8*)&z0[(size_t)c2 * DIM + sl * 8];
            short8 v3 = *(const short8*)&z0[(size_t)c3 * DIM + sl * 8];
#pragma unroll
            for (int j = 0; j < 8; ++j)
                acc[j] += (bf2f(v0[j]) + bf2f(v1[j])) + (bf2f(v2[j]) + bf2f(v3[j]));
        }
        for (; it + 4 < e; it += 8) {
            int c0 = adj[it];
            int c1 = adj[it + 4];
            short8 v0 = *(const short8*)&z0[(size_t)c0 * DIM + sl * 8];
            short8 v1 = *(const short8*)&z0[(size_t)c1 * DIM + sl * 8];
#pragma unroll
            for (int j = 0; j < 8; ++j) acc[j] += bf2f(v0[j]) + bf2f(v1[j]);
        }
        if (it < e) {
            int c = adj[it];
            short8 v = *(const short8*)&z0[(size_t)c * DIM + sl * 8];
#pragma unroll
            for (int j = 0; j < 8; ++j) acc[j] += bf2f(v[j]);
        }

#pragma unroll
        for (int j = 0; j < 8; ++j) acc[j] += __shfl_xor(acc[j], 16, 64);
#pragma unroll
        for (int j = 0; j < 8; ++j) acc[j] += __shfl_xor(acc[j], 32, 64);

        if (quad == 0) {
            float* hp = H + (size_t)node * DIM + sl * 8;
            float4 h0 = *(float4*)hp;
            float4 h1 = *(float4*)(hp + 4);
            float4 b0v = *(const float4*)&bias[sl * 8];
            float4 b1v = *(const float4*)&bias[sl * 8 + 4];
            float r[8];
            r[0] = acc[0] + b0v.x; r[1] = acc[1] + b0v.y; r[2] = acc[2] + b0v.z; r[3] = acc[3] + b0v.w;
            r[4] = acc[4] + b1v.x; r[5] = acc[5] + b1v.y; r[6] = acc[6] + b1v.z; r[7] = acc[7] + b1v.w;
            float hn[8];
            hn[0] = h0.x; hn[1] = h0.y; hn[2] = h0.z; hn[3] = h0.w;
            hn[4] = h1.x; hn[5] = h1.y; hn[6] = h1.z; hn[7] = h1.w;
            short8 o;
#pragma unroll
            for (int j = 0; j < 8; ++j) {
                float rr = r[j] > 0.f ? r[j] : 0.f;
                hn[j] += rr;
                o[j] = f2bf(hn[j]);
            }
            *(float4*)hp       = make_float4(hn[0], hn[1], hn[2], hn[3]);
            *(float4*)(hp + 4) = make_float4(hn[4], hn[5], hn[6], hn[7]);
            *(short8*)&hs[m][sl * 8] = o;
        }
    }
    __syncthreads();

    // phase 2: Z1[16x128] = hs @ W1 ; wave handles cols [wave*32, wave*32+32)
    f32x4 acc2[2];
    acc2[0] = (f32x4){0.f, 0.f, 0.f, 0.f};
    acc2[1] = (f32x4){0.f, 0.f, 0.f, 0.f};
#pragma unroll
    for (int kb = 0; kb < 4; ++kb) {
        short8 afrag = *(const short8*)&hs[sl][kb * 32 + quad * 8];
#pragma unroll
        for (int nt2 = 0; nt2 < 2; ++nt2) {
            int nt = wave * 2 + nt2;
            short8 bfrag = *(const short8*)&W1F[((kb * 8 + nt) * 64 + l) * 8];
            acc2[nt2] = __builtin_amdgcn_mfma_f32_16x16x32_bf16(afrag, bfrag, acc2[nt2], 0, 0, 0);
        }
    }
#pragma unroll
    for (int nt2 = 0; nt2 < 2; ++nt2) {
        int col = (wave * 2 + nt2) * 16 + sl;
#pragma unroll
        for (int r = 0; r < 4; ++r) {
            int row = nodeBase + quad * 4 + r;
            float v = acc2[nt2][r];
            int packed = __builtin_amdgcn_cvt_pk_fp8_f32(v, v, 0, false);
            Z1[(size_t)row * 128 + col] = (unsigned char)(packed & 0xFF);
        }
    }
}

// ---------------------------------------------------------------------------
// Dispatch 6: final aggregation over fp8 Z1.
// H[node] += relu(agg(Z1)+b1), own row only.
// ---------------------------------------------------------------------------
__global__ __launch_bounds__(256) void agg_final(const unsigned char* __restrict__ z1,
                                                 const int* __restrict__ row_ptr,
                                                 const unsigned short* __restrict__ adj,
                                                 const float* __restrict__ bias,
                                                 float* __restrict__ H) {
    const int wave = threadIdx.x >> 6;
    const int l    = threadIdx.x & 63;
    const int quad = l >> 4;
    const int sl   = l & 15;
    const int node = blockIdx.x * 4 + wave;
    if (node >= N_NODES) return;

    const int s = row_ptr[node];
    const int e = row_ptr[node + 1];

    float acc[8];
#pragma unroll
    for (int j = 0; j < 8; ++j) acc[j] = 0.f;

#define ADD_FP8(u2)                                                          \
    {                                                                        \
        f32x2 a0 = __builtin_amdgcn_cvt_pk_f32_fp8((u2).x, false);           \
        f32x2 a1 = __builtin_amdgcn_cvt_pk_f32_fp8((u2).x, true);            \
        f32x2 a2 = __builtin_amdgcn_cvt_pk_f32_fp8((u2).y, false);           \
        f32x2 a3 = __builtin_amdgcn_cvt_pk_f32_fp8((u2).y, true);            \
        acc[0] += a0.x; acc[1] += a0.y; acc[2] += a1.x; acc[3] += a1.y;      \
        acc[4] += a2.x; acc[5] += a2.y; acc[6] += a3.x; acc[7] += a3.y;      \
    }

    int it = s + quad;
    for (; it + 12 < e; it += 16) {
        int c0 = adj[it];
        int c1 = adj[it + 4];
        int c2 = adj[it + 8];
        int c3 = adj[it + 12];
        uint2 v0 = *(const uint2*)&z1[(size_t)c0 * 128 + sl * 8];
        uint2 v1 = *(const uint2*)&z1[(size_t)c1 * 128 + sl * 8];
        uint2 v2 = *(const uint2*)&z1[(size_t)c2 * 128 + sl * 8];
        uint2 v3 = *(const uint2*)&z1[(size_t)c3 * 128 + sl * 8];
        ADD_FP8(v0); ADD_FP8(v1); ADD_FP8(v2); ADD_FP8(v3);
    }
    for (; it + 4 < e; it += 8) {
        int c0 = adj[it];
        int c1 = adj[it + 4];
        uint2 v0 = *(const uint2*)&z1[(size_t)c0 * 128 + sl * 8];
        uint2 v1 = *(const uint2*)&z1[(size_t)c1 * 128 + sl * 8];
        ADD_FP8(v0); ADD_FP8(v1);
    }
    if (it < e) {
        int c = adj[it];
        uint2 v = *(const uint2*)&z1[(size_t)c * 128 + sl * 8];
        ADD_FP8(v);
    }
#undef ADD_FP8

#pragma unroll
    for (int j = 0; j < 8; ++j) acc[j] += __shfl_xor(acc[j], 16, 64);
#pragma unroll
    for (int j = 0; j < 8; ++j) acc[j] += __shfl_xor(acc[j], 32, 64);

    if (quad == 0) {
        float* hp = H + (size_t)node * DIM + sl * 8;
        float4 h0 = *(float4*)hp;
        float4 h1 = *(float4*)(hp + 4);
        float4 b0 = *(const float4*)&bias[sl * 8];
        float4 b1 = *(const float4*)&bias[sl * 8 + 4];
        float r0 = acc[0] + b0.x, r1 = acc[1] + b0.y, r2 = acc[2] + b0.z, r3 = acc[3] + b0.w;
        float r4 = acc[4] + b1.x, r5 = acc[5] + b1.y, r6 = acc[6] + b1.z, r7 = acc[7] + b1.w;
        h0.x += r0 > 0.f ? r0 : 0.f;  h0.y += r1 > 0.f ? r1 : 0.f;
        h0.z += r2 > 0.f ? r2 : 0.f;  h0.w += r3 > 0.f ? r3 : 0.f;
        h1.x += r4 > 0.f ? r4 : 0.f;  h1.y += r5 > 0.f ? r5 : 0.f;
        h1.z += r6 > 0.f ? r6 : 0.f;  h1.w += r7 > 0.f ? r7 : 0.f;
        *(float4*)hp       = h0;
        *(float4*)(hp + 4) = h1;
    }
}

// ---------------------------------------------------------------------------
extern "C" void kernel_launch(void* const* d_in, const int* in_sizes, int n_in,
                              void* d_out, int out_size, void* d_ws, size_t ws_size,
                              hipStream_t stream) {
    const float* x   = (const float*)d_in[0];
    const int*   ei  = (const int*)d_in[1];
    const float* W_t = (const float*)d_in[2];
    const float* b_t = (const float*)d_in[3];
    const float* W0  = (const float*)d_in[4];
    const float* b0  = (const float*)d_in[5];
    const float* W1  = (const float*)d_in[6];
    const float* b1  = (const float*)d_in[7];

    const int* rows = ei;
    const int* cols = ei + N_EDGES;

    float* H = (float*)d_out;   // fp32 h lives here the whole time

    // workspace layout (~20 MB)
    char* w = (char*)d_ws;
    __hip_bfloat16* Z0 = (__hip_bfloat16*)w;  w += (size_t)N_NODES * DIM * 2;
    unsigned char*  Z1 = (unsigned char*)w;   w += (size_t)N_NODES * DIM;      // fp8
    short* WtF = (short*)w;  w += 128 * 128 * 2;
    short* WfF = (short*)w;  w += 128 * 128 * 2;
    short* W1F = (short*)w;  w += 128 * 128 * 2;
    float* btf = (float*)w;  w += 128 * 4;
    int* row_ptr = (int*)w;  w += (N_NODES + 1) * 4;
    int* counts4 = (int*)w;  w += NREP * N_NODES * 4;
    int* absOff  = (int*)w;  w += NREP * N_NODES * 4;
    int* flags   = (int*)w;  w += 256 * 4;
    int* totals  = (int*)w;  w += 256 * 4;
    unsigned short* rank = (unsigned short*)w;  w += (size_t)N_EDGES * 2;
    unsigned short* adj  = (unsigned short*)w;  // E u16

    const int aggBlocks = (N_NODES + 3) / 4;

    // 1: weight prep | zero counts4 | zero flags+totals
    prep_zero<<<64 + NREP * NB + 1, 256, 0, stream>>>(W_t, W0, W1, b_t, WtF, WfF,
                                                      W1F, btf, counts4, flags);

    // 2: replicated histogram+rank | dual GEMM over x
    histrank_gemm<<<HEB + GEMMB, 256, 0, stream>>>(rows, counts4, rank,
                                                   x, WtF, WfF, b_t, btf, H, Z0);

    // 3: single-pass scan -> row_ptr + absOff
    scan_onepass<<<NB, 256, 0, stream>>>(counts4, flags, totals, row_ptr, absOff);

    // 4: atomic-free scatter
    scatter_plain<<<HEB, 256, 0, stream>>>(rows, cols, rank, absOff, adj);

    // 5: layer-0 agg + layer-1 GEMM fused: H += relu(agg(Z0)+b0); Z1 = fp8(bf16(H)@W1)
    agg0_gemm<<<N_NODES / 16, 256, 0, stream>>>(Z0, row_ptr, adj, b0, W1F, H, Z1);

    // 6: final agg (fp8 gather): H += relu(agg(Z1) + b1)
    agg_final<<<aggBlocks, 256, 0, stream>>>(Z1, row_ptr, adj, b1, H);
}

// Round 11
// 185.162 us; speedup vs baseline: 1.2540x; 1.0770x over previous
//
#include <hip/hip_runtime.h>
#include <hip/hip_bf16.h>

#define N_NODES 40000
#define N_EDGES 640000
#define DIM     128
#define NB      157    // node blocks (256 threads)
#define GEMMB   625    // gemm blocks (64 rows each)
#define HEB     1250   // scatter blocks (2 edges/thread)
#define CHUNKS  64     // hist chunks (one block each)
#define CHUNK_E 10000  // edges per chunk
#define LDSW    10000  // u32 words packing 40000 u8 counters

typedef __attribute__((ext_vector_type(8))) short short8;
typedef __attribute__((ext_vector_type(4))) float f32x4;
typedef __attribute__((ext_vector_type(2))) float f32x2;

__device__ inline short f2bf(float f) {
    __hip_bfloat16 h = __float2bfloat16(f);
    return *reinterpret_cast<short*>(&h);
}
__device__ inline float bf2f(short u) {
    union { unsigned int i; float f; } x;
    x.i = ((unsigned int)(unsigned short)u) << 16;
    return x.f;
}

// fragment-order index for element (k,n) of a 128x128 W, matching the
// MFMA B-fragment read: lane l reads slot (kb*8+nt)*64 + l as short8.
__device__ inline int fragidx(int k, int n) {
    int kb = k >> 5, kq = (k >> 3) & 3, j = k & 7;
    int nt = n >> 4, nl = n & 15;
    return (((kb * 8 + nt) * 64 + kq * 16 + nl) * 8 + j);
}

// ---------------------------------------------------------------------------
// Dispatch 1: [0,64) weight prep; block 64 zeros flags+totals.
// (counts now live in LDS — nothing big to zero.)
// ---------------------------------------------------------------------------
__global__ __launch_bounds__(256) void prep_zero(const float* __restrict__ Wt,
                                                 const float* __restrict__ W0,
                                                 const float* __restrict__ W1,
                                                 const float* __restrict__ bt,
                                                 short* __restrict__ WtF,
                                                 short* __restrict__ WfF,
                                                 short* __restrict__ W1F,
                                                 float* __restrict__ btf,
                                                 int* __restrict__ flagtot) {
    int b = blockIdx.x;
    if (b < 64) {
        int gid = b * 256 + threadIdx.x;            // 0..16383
        int k = gid >> 7, n = gid & 127;
        float wf = 0.f;
        for (int kk = 0; kk < 128; ++kk)
            wf += Wt[k * 128 + kk] * W0[kk * 128 + n];
        int fi = fragidx(k, n);
        WtF[fi] = f2bf(Wt[k * 128 + n]);
        W1F[fi] = f2bf(W1[k * 128 + n]);
        WfF[fi] = f2bf(wf);
        if (gid < 128) {
            float s = 0.f;
            for (int kk = 0; kk < 128; ++kk) s += bt[kk] * W0[kk * 128 + n];
            btf[n] = s;
        }
    } else {
        flagtot[threadIdx.x]       = 0;   // flags
        flagtot[threadIdx.x + 256] = 0;   // totals
    }
}

// ---------------------------------------------------------------------------
// Dispatch 2: blocks [0,CHUNKS) = LDS histogram of one 10000-edge chunk
// (u8 counters packed 4-per-u32; returning LDS atomicAdd gives rank within
// chunk-bucket — NO global atomics). Writes rank8[e] + per-chunk counts.
// Blocks [CHUNKS, CHUNKS+GEMMB) = dual GEMM over x:
//   H = x@Wt + bt (fp32, d_out), Z0 = bf16(x@(Wt@W0) + bt@W0)
// ---------------------------------------------------------------------------
__global__ __launch_bounds__(256) void histlds_gemm(const int* __restrict__ rows,
                                                    unsigned char* __restrict__ rank8,
                                                    unsigned int* __restrict__ cnt8w,
                                                    const float* __restrict__ A,
                                                    const short* __restrict__ WtF,
                                                    const short* __restrict__ WfF,
                                                    const float* __restrict__ bt,
                                                    const float* __restrict__ btf,
                                                    float* __restrict__ H,
                                                    __hip_bfloat16* __restrict__ Z) {
    __shared__ unsigned int lcnt[LDSW];   // 40 KB (all blocks reserve it)

    if (blockIdx.x < CHUNKS) {
        for (int i = threadIdx.x; i < LDSW; i += 256) lcnt[i] = 0u;
        __syncthreads();
        const int base = blockIdx.x * CHUNK_E;
#pragma unroll
        for (int i = 0; i < 40; ++i) {
            int o = i * 256 + threadIdx.x;
            if (o < CHUNK_E) {
                int e = base + o;
                int r = rows[e];
                unsigned int sh = (unsigned int)(r & 3) * 8u;
                unsigned int old = atomicAdd(&lcnt[r >> 2], 1u << sh);
                rank8[e] = (unsigned char)((old >> sh) & 0xFFu);
            }
        }
        __syncthreads();
        unsigned int* out = cnt8w + blockIdx.x * LDSW;
        for (int i = threadIdx.x; i < LDSW; i += 256) out[i] = lcnt[i];
        return;
    }

    const int t    = threadIdx.x;
    const int wave = t >> 6;
    const int l    = t & 63;
    const int nl   = l & 15;
    const int quad = l >> 4;
    const int wRow = (blockIdx.x - CHUNKS) * 64 + wave * 16;

    f32x4 accH[8], accZ[8];
#pragma unroll
    for (int nt = 0; nt < 8; ++nt) {
        accH[nt] = (f32x4){0.f, 0.f, 0.f, 0.f};
        accZ[nt] = (f32x4){0.f, 0.f, 0.f, 0.f};
    }

#pragma unroll
    for (int kb = 0; kb < 4; ++kb) {
        const float* ap = A + (size_t)(wRow + nl) * 128 + kb * 32 + quad * 8;
        float4 f0 = *(const float4*)ap;
        float4 f1 = *(const float4*)(ap + 4);
        short8 afrag;
        afrag[0] = f2bf(f0.x); afrag[1] = f2bf(f0.y);
        afrag[2] = f2bf(f0.z); afrag[3] = f2bf(f0.w);
        afrag[4] = f2bf(f1.x); afrag[5] = f2bf(f1.y);
        afrag[6] = f2bf(f1.z); afrag[7] = f2bf(f1.w);
#pragma unroll
        for (int nt = 0; nt < 8; ++nt) {
            int off = ((kb * 8 + nt) * 64 + l) * 8;
            short8 bt_frag = *(const short8*)&WtF[off];
            short8 bf_frag = *(const short8*)&WfF[off];
            accH[nt] = __builtin_amdgcn_mfma_f32_16x16x32_bf16(afrag, bt_frag, accH[nt], 0, 0, 0);
            accZ[nt] = __builtin_amdgcn_mfma_f32_16x16x32_bf16(afrag, bf_frag, accZ[nt], 0, 0, 0);
        }
    }

#pragma unroll
    for (int nt = 0; nt < 8; ++nt) {
        int col = nt * 16 + nl;
        float bH = bt[col];
        float bZ = btf[col];
#pragma unroll
        for (int r = 0; r < 4; ++r) {
            int row = wRow + quad * 4 + r;
            H[(size_t)row * 128 + col] = accH[nt][r] + bH;
            *(short*)&Z[(size_t)row * 128 + col] = f2bf(accZ[nt][r] + bZ);
        }
    }
}

// ---------------------------------------------------------------------------
// Dispatch 3: single-pass scan. Per node: degree = sum of 64 chunk counts;
// global prefix via publish-then-spin (proven R9/R10); then convert chunk
// counts -> chunk prefixes IN PLACE (u8: max degree << 256). row_ptr out.
// ---------------------------------------------------------------------------
__global__ __launch_bounds__(256) void scan_onepass(unsigned char* __restrict__ cnt8,
                                                    int* __restrict__ flags,
                                                    int* __restrict__ totals,
                                                    int* __restrict__ row_ptr) {
    __shared__ int sh[256];
    const int b = blockIdx.x;
    const int t = threadIdx.x;
    const int i = b * 256 + t;

    int deg = 0;
    if (i < N_NODES) {
#pragma unroll 8
        for (int c = 0; c < CHUNKS; ++c) deg += cnt8[(size_t)c * N_NODES + i];
    }

    int val = deg;
    sh[t] = val;
    __syncthreads();
    for (int off = 1; off < 256; off <<= 1) {
        int a = (t >= off) ? sh[t - off] : 0;
        __syncthreads();
        val += a;
        sh[t] = val;
        __syncthreads();
    }
    const int excl  = val - deg;
    const int total = sh[255];

    if (t == 0) {
        atomicExch(&totals[b], total);
        __threadfence();
        atomicExch(&flags[b], 1);
    }

    int v = 0;
    if (t < NB) {
        while (atomicAdd(&flags[t], 0) == 0) { }
        v = atomicAdd(&totals[t], 0);
    }
    __syncthreads();
    int val2 = v;
    sh[t] = val2;
    __syncthreads();
    for (int off = 1; off < 256; off <<= 1) {
        int a = (t >= off) ? sh[t - off] : 0;
        __syncthreads();
        val2 += a;
        sh[t] = val2;
        __syncthreads();
    }
    int blkOff = (b == 0) ? 0 : sh[b - 1];

    if (i < N_NODES) {
        int base = excl + blkOff;
        row_ptr[i] = base;
        int run = 0;
#pragma unroll 8
        for (int c = 0; c < CHUNKS; ++c) {
            int cv = cnt8[(size_t)c * N_NODES + i];
            cnt8[(size_t)c * N_NODES + i] = (unsigned char)run;
            run += cv;
        }
    }
    if (i == 0) row_ptr[N_NODES] = N_EDGES;
}

// ---------------------------------------------------------------------------
// Dispatch 4: fully atomic-free scatter.
// pos = row_ptr[r] + pref8[chunk][r] + rank8[e].
// ---------------------------------------------------------------------------
__global__ __launch_bounds__(256) void scatter_plain(const int* __restrict__ rows,
                                                     const int* __restrict__ cols,
                                                     const unsigned char* __restrict__ rank8,
                                                     const unsigned char* __restrict__ pref8,
                                                     const int* __restrict__ row_ptr,
                                                     unsigned short* __restrict__ adj) {
    int gid = blockIdx.x * 256 + threadIdx.x;     // 0..319999
#pragma unroll
    for (int h = 0; h < 2; ++h) {
        int e = gid + h * HEB * 256;
        int r = rows[e];
        int c = e / CHUNK_E;
        int pos = row_ptr[r] + (int)pref8[(size_t)c * N_NODES + r] + (int)rank8[e];
        adj[pos] = (unsigned short)cols[e];
    }
}

// ---------------------------------------------------------------------------
// Dispatch 5: fused layer-0 agg + layer-1 GEMM.
// Phase 1: gather Z0 (bf16), H += relu(agg+b0) in place, stage bf16(hnew)
// in padded LDS. Phase 2: Z1[16x128] = hs @ W1 -> fp8 e4m3 (HW cvt).
// ---------------------------------------------------------------------------
__global__ __launch_bounds__(256) void agg0_gemm(const __hip_bfloat16* __restrict__ z0,
                                                 const int* __restrict__ row_ptr,
                                                 const unsigned short* __restrict__ adj,
                                                 const float* __restrict__ bias,
                                                 const short* __restrict__ W1F,
                                                 float* __restrict__ H,
                                                 unsigned char* __restrict__ Z1) {
    __shared__ short hs[16][136];   // +8 shorts pad

    const int t    = threadIdx.x;
    const int wave = t >> 6;
    const int l    = t & 63;
    const int quad = l >> 4;
    const int sl   = l & 15;
    const int nodeBase = blockIdx.x * 16;

#pragma unroll
    for (int u = 0; u < 4; ++u) {
        const int m    = wave * 4 + u;
        const int node = nodeBase + m;
        const int s = row_ptr[node];
        const int e = row_ptr[node + 1];

        float acc[8];
#pragma unroll
        for (int j = 0; j < 8; ++j) acc[j] = 0.f;

        int it = s + quad;
        for (; it + 12 < e; it += 16) {
            int c0 = adj[it];
            int c1 = adj[it + 4];
            int c2 = adj[it + 8];
            int c3 = adj[it + 12];
            short8 v0 = *(const short8*)&z0[(size_t)c0 * DIM + sl * 8];
            short8 v1 = *(const short8*)&z0[(size_t)c1 * DIM + sl * 8];
            short8 v2 = *(const short8*)&z0[(size_t)c2 * DIM + sl * 8];
            short8 v3 = *(const short8*)&z0[(size_t)c3 * DIM + sl * 8];
#pragma unroll
            for (int j = 0; j < 8; ++j)
                acc[j] += (bf2f(v0[j]) + bf2f(v1[j])) + (bf2f(v2[j]) + bf2f(v3[j]));
        }
        for (; it + 4 < e; it += 8) {
            int c0 = adj[it];
            int c1 = adj[it + 4];
            short8 v0 = *(const short8*)&z0[(size_t)c0 * DIM + sl * 8];
            short8 v1 = *(const short8*)&z0[(size_t)c1 * DIM + sl * 8];
#pragma unroll
            for (int j = 0; j < 8; ++j) acc[j] += bf2f(v0[j]) + bf2f(v1[j]);
        }
        if (it < e) {
            int c = adj[it];
            short8 v = *(const short8*)&z0[(size_t)c * DIM + sl * 8];
#pragma unroll
            for (int j = 0; j < 8; ++j) acc[j] += bf2f(v[j]);
        }

#pragma unroll
        for (int j = 0; j < 8; ++j) acc[j] += __shfl_xor(acc[j], 16, 64);
#pragma unroll
        for (int j = 0; j < 8; ++j) acc[j] += __shfl_xor(acc[j], 32, 64);

        if (quad == 0) {
            float* hp = H + (size_t)node * DIM + sl * 8;
            float4 h0 = *(float4*)hp;
            float4 h1 = *(float4*)(hp + 4);
            float4 b0v = *(const float4*)&bias[sl * 8];
            float4 b1v = *(const float4*)&bias[sl * 8 + 4];
            float r[8];
            r[0] = acc[0] + b0v.x; r[1] = acc[1] + b0v.y; r[2] = acc[2] + b0v.z; r[3] = acc[3] + b0v.w;
            r[4] = acc[4] + b1v.x; r[5] = acc[5] + b1v.y; r[6] = acc[6] + b1v.z; r[7] = acc[7] + b1v.w;
            float hn[8];
            hn[0] = h0.x; hn[1] = h0.y; hn[2] = h0.z; hn[3] = h0.w;
            hn[4] = h1.x; hn[5] = h1.y; hn[6] = h1.z; hn[7] = h1.w;
            short8 o;
#pragma unroll
            for (int j = 0; j < 8; ++j) {
                float rr = r[j] > 0.f ? r[j] : 0.f;
                hn[j] += rr;
                o[j] = f2bf(hn[j]);
            }
            *(float4*)hp       = make_float4(hn[0], hn[1], hn[2], hn[3]);
            *(float4*)(hp + 4) = make_float4(hn[4], hn[5], hn[6], hn[7]);
            *(short8*)&hs[m][sl * 8] = o;
        }
    }
    __syncthreads();

    // phase 2: Z1[16x128] = hs @ W1 ; wave handles cols [wave*32, wave*32+32)
    f32x4 acc2[2];
    acc2[0] = (f32x4){0.f, 0.f, 0.f, 0.f};
    acc2[1] = (f32x4){0.f, 0.f, 0.f, 0.f};
#pragma unroll
    for (int kb = 0; kb < 4; ++kb) {
        short8 afrag = *(const short8*)&hs[sl][kb * 32 + quad * 8];
#pragma unroll
        for (int nt2 = 0; nt2 < 2; ++nt2) {
            int nt = wave * 2 + nt2;
            short8 bfrag = *(const short8*)&W1F[((kb * 8 + nt) * 64 + l) * 8];
            acc2[nt2] = __builtin_amdgcn_mfma_f32_16x16x32_bf16(afrag, bfrag, acc2[nt2], 0, 0, 0);
        }
    }
#pragma unroll
    for (int nt2 = 0; nt2 < 2; ++nt2) {
        int col = (wave * 2 + nt2) * 16 + sl;
#pragma unroll
        for (int r = 0; r < 4; ++r) {
            int row = nodeBase + quad * 4 + r;
            float v = acc2[nt2][r];
            int packed = __builtin_amdgcn_cvt_pk_fp8_f32(v, v, 0, false);
            Z1[(size_t)row * 128 + col] = (unsigned char)(packed & 0xFF);
        }
    }
}

// ---------------------------------------------------------------------------
// Dispatch 6: final aggregation over fp8 Z1.
// H[node] += relu(agg(Z1)+b1), own row only.
// ---------------------------------------------------------------------------
__global__ __launch_bounds__(256) void agg_final(const unsigned char* __restrict__ z1,
                                                 const int* __restrict__ row_ptr,
                                                 const unsigned short* __restrict__ adj,
                                                 const float* __restrict__ bias,
                                                 float* __restrict__ H) {
    const int wave = threadIdx.x >> 6;
    const int l    = threadIdx.x & 63;
    const int quad = l >> 4;
    const int sl   = l & 15;
    const int node = blockIdx.x * 4 + wave;
    if (node >= N_NODES) return;

    const int s = row_ptr[node];
    const int e = row_ptr[node + 1];

    float acc[8];
#pragma unroll
    for (int j = 0; j < 8; ++j) acc[j] = 0.f;

#define ADD_FP8(u2)                                                          \
    {                                                                        \
        f32x2 a0 = __builtin_amdgcn_cvt_pk_f32_fp8((u2).x, false);           \
        f32x2 a1 = __builtin_amdgcn_cvt_pk_f32_fp8((u2).x, true);            \
        f32x2 a2 = __builtin_amdgcn_cvt_pk_f32_fp8((u2).y, false);           \
        f32x2 a3 = __builtin_amdgcn_cvt_pk_f32_fp8((u2).y, true);            \
        acc[0] += a0.x; acc[1] += a0.y; acc[2] += a1.x; acc[3] += a1.y;      \
        acc[4] += a2.x; acc[5] += a2.y; acc[6] += a3.x; acc[7] += a3.y;      \
    }

    int it = s + quad;
    for (; it + 12 < e; it += 16) {
        int c0 = adj[it];
        int c1 = adj[it + 4];
        int c2 = adj[it + 8];
        int c3 = adj[it + 12];
        uint2 v0 = *(const uint2*)&z1[(size_t)c0 * 128 + sl * 8];
        uint2 v1 = *(const uint2*)&z1[(size_t)c1 * 128 + sl * 8];
        uint2 v2 = *(const uint2*)&z1[(size_t)c2 * 128 + sl * 8];
        uint2 v3 = *(const uint2*)&z1[(size_t)c3 * 128 + sl * 8];
        ADD_FP8(v0); ADD_FP8(v1); ADD_FP8(v2); ADD_FP8(v3);
    }
    for (; it + 4 < e; it += 8) {
        int c0 = adj[it];
        int c1 = adj[it + 4];
        uint2 v0 = *(const uint2*)&z1[(size_t)c0 * 128 + sl * 8];
        uint2 v1 = *(const uint2*)&z1[(size_t)c1 * 128 + sl * 8];
        ADD_FP8(v0); ADD_FP8(v1);
    }
    if (it < e) {
        int c = adj[it];
        uint2 v = *(const uint2*)&z1[(size_t)c * 128 + sl * 8];
        ADD_FP8(v);
    }
#undef ADD_FP8

#pragma unroll
    for (int j = 0; j < 8; ++j) acc[j] += __shfl_xor(acc[j], 16, 64);
#pragma unroll
    for (int j = 0; j < 8; ++j) acc[j] += __shfl_xor(acc[j], 32, 64);

    if (quad == 0) {
        float* hp = H + (size_t)node * DIM + sl * 8;
        float4 h0 = *(float4*)hp;
        float4 h1 = *(float4*)(hp + 4);
        float4 b0 = *(const float4*)&bias[sl * 8];
        float4 b1 = *(const float4*)&bias[sl * 8 + 4];
        float r0 = acc[0] + b0.x, r1 = acc[1] + b0.y, r2 = acc[2] + b0.z, r3 = acc[3] + b0.w;
        float r4 = acc[4] + b1.x, r5 = acc[5] + b1.y, r6 = acc[6] + b1.z, r7 = acc[7] + b1.w;
        h0.x += r0 > 0.f ? r0 : 0.f;  h0.y += r1 > 0.f ? r1 : 0.f;
        h0.z += r2 > 0.f ? r2 : 0.f;  h0.w += r3 > 0.f ? r3 : 0.f;
        h1.x += r4 > 0.f ? r4 : 0.f;  h1.y += r5 > 0.f ? r5 : 0.f;
        h1.z += r6 > 0.f ? r6 : 0.f;  h1.w += r7 > 0.f ? r7 : 0.f;
        *(float4*)hp       = h0;
        *(float4*)(hp + 4) = h1;
    }
}

// ---------------------------------------------------------------------------
extern "C" void kernel_launch(void* const* d_in, const int* in_sizes, int n_in,
                              void* d_out, int out_size, void* d_ws, size_t ws_size,
                              hipStream_t stream) {
    const float* x   = (const float*)d_in[0];
    const int*   ei  = (const int*)d_in[1];
    const float* W_t = (const float*)d_in[2];
    const float* b_t = (const float*)d_in[3];
    const float* W0  = (const float*)d_in[4];
    const float* b0  = (const float*)d_in[5];
    const float* W1  = (const float*)d_in[6];
    const float* b1  = (const float*)d_in[7];

    const int* rows = ei;
    const int* cols = ei + N_EDGES;

    float* H = (float*)d_out;   // fp32 h lives here the whole time

    // workspace layout (~20 MB)
    char* w = (char*)d_ws;
    __hip_bfloat16* Z0 = (__hip_bfloat16*)w;  w += (size_t)N_NODES * DIM * 2;
    unsigned char*  Z1 = (unsigned char*)w;   w += (size_t)N_NODES * DIM;      // fp8
    short* WtF = (short*)w;  w += 128 * 128 * 2;
    short* WfF = (short*)w;  w += 128 * 128 * 2;
    short* W1F = (short*)w;  w += 128 * 128 * 2;
    float* btf = (float*)w;  w += 128 * 4;
    int* row_ptr = (int*)w;  w += (N_NODES + 1) * 4;
    int* flags   = (int*)w;  w += 256 * 4;
    int* totals  = (int*)w;  w += 256 * 4;
    unsigned int* cnt8w = (unsigned int*)w;  w += (size_t)CHUNKS * LDSW * 4;  // 2.56 MB
    unsigned char* rank8 = (unsigned char*)w;  w += (size_t)N_EDGES;          // 640 KB
    unsigned short* adj  = (unsigned short*)w;  // E u16

    const int aggBlocks = (N_NODES + 3) / 4;

    // 1: weight prep | zero flags+totals
    prep_zero<<<65, 256, 0, stream>>>(W_t, W0, W1, b_t, WtF, WfF, W1F, btf, flags);

    // 2: LDS chunk histograms (no global atomics) | dual GEMM over x
    histlds_gemm<<<CHUNKS + GEMMB, 256, 0, stream>>>(rows, rank8, cnt8w,
                                                     x, WtF, WfF, b_t, btf, H, Z0);

    // 3: single-pass scan -> row_ptr; chunk counts -> chunk prefixes in place
    scan_onepass<<<NB, 256, 0, stream>>>((unsigned char*)cnt8w, flags, totals, row_ptr);

    // 4: atomic-free scatter
    scatter_plain<<<HEB, 256, 0, stream>>>(rows, cols, rank8, (unsigned char*)cnt8w,
                                           row_ptr, adj);

    // 5: layer-0 agg + layer-1 GEMM fused: H += relu(agg(Z0)+b0); Z1 = fp8(bf16(H)@W1)
    agg0_gemm<<<N_NODES / 16, 256, 0, stream>>>(Z0, row_ptr, adj, b0, W1F, H, Z1);

    // 6: final agg (fp8 gather): H += relu(agg(Z1) + b1)
    agg_final<<<aggBlocks, 256, 0, stream>>>(Z1, row_ptr, adj, b1, H);
}